// Round 4
// baseline (720.859 us; speedup 1.0000x reference)
//
#include <hip/hip_runtime.h>

namespace {

constexpr int kS = 1024;
constexpr int kD = 64;
constexpr int kH = 128;

typedef __attribute__((ext_vector_type(2))) _Float16 half2v;
typedef __attribute__((ext_vector_type(4))) float f32x4;
typedef __attribute__((ext_vector_type(8))) _Float16 half8;

__device__ __forceinline__ float fdot2(unsigned w, unsigned h, float acc) {
#if __has_builtin(__builtin_amdgcn_fdot2)
  return __builtin_amdgcn_fdot2(__builtin_bit_cast(half2v, w),
                                __builtin_bit_cast(half2v, h), acc, false);
#else
  float d;
  asm("v_dot2_f32_f16 %0, %1, %2, %3" : "=v"(d) : "v"(w), "v"(h), "v"(acc));
  return d;
#endif
}

// uniform lane-broadcast of a packed-f16 dword (register -> SGPR, no LDS)
__device__ __forceinline__ unsigned rdlane(unsigned v, int k) {
#if __has_builtin(__builtin_amdgcn_readlane)
  return (unsigned)__builtin_amdgcn_readlane((int)v, k);
#else
  return (unsigned)__shfl((int)v, k, 64);
#endif
}

// RNE f16 pack (cvt_pkrtz is RTZ -> systematic shrink bias over 1024 steps)
__device__ __forceinline__ unsigned pk16(float a, float b) {
  half2v h;
  h.x = (_Float16)a;
  h.y = (_Float16)b;
  return __builtin_bit_cast(unsigned, h);
}

__device__ __forceinline__ float fast_tanh(float x) {
  x = fminf(fmaxf(x, -15.f), 15.f);
  float e = __expf(2.f * x);
  return (e - 1.f) * __builtin_amdgcn_rcpf(e + 1.f);
}

#if __has_builtin(__builtin_amdgcn_mov_dpp)
__device__ __forceinline__ float lane_xor1(float v) {
  return __int_as_float(__builtin_amdgcn_mov_dpp(__float_as_int(v), 0xB1, 0xF, 0xF, true));
}
#else
__device__ __forceinline__ float lane_xor1(float v) {
  return __int_as_float(__builtin_amdgcn_ds_swizzle(__float_as_int(v), 0x041F));
}
#endif

// lgkm-drain + raw barrier: orders LDS write->cross-wave-read WITHOUT the
// vmcnt(0) drain __syncthreads would add (keeps xp prefetch in flight).
__device__ __forceinline__ void wave_sync() {
  asm volatile("s_waitcnt lgkmcnt(0)\n\ts_barrier" ::: "memory");
}

// async global->LDS, 4 x 16B/lane = this wave's 4 KB half of an 8 KB xp chunk
__device__ __forceinline__ void stage_half(const char* g, unsigned* lds, int L, int w) {
#pragma unroll
  for (int k = 0; k < 4; ++k) {
    const int kk = 4 * w + k;
    __builtin_amdgcn_global_load_lds(
        (const __attribute__((address_space(1))) void*)(g + kk * 1024 + L * 16),
        (__attribute__((address_space(3))) void*)(lds + kk * 256), 16, 0, 0);
  }
}

// xp (f16) layout per (dir,b) slab of kS*kH elems, chunk-transposed:
//   idx = (t>>5)*(32*kH) + (t&31)*kH + j     (dir=1 pre-time-reversed)
// -> one 32-step chunk = 8 KB contiguous, DMA-stageable.

// =====================  Phase A: x-projection via f16 MFMA  =====================
// (unchanged: 84 us, correct)
__global__ __launch_bounds__(256, 2) void xproj_kernel(
    const float* __restrict__ inputs,
    const float* __restrict__ Wih_fw, const float* __restrict__ bih_fw,
    const float* __restrict__ bhh_fw,
    const float* __restrict__ Wih_bw, const float* __restrict__ bih_bw,
    const float* __restrict__ bhh_bw,
    _Float16* __restrict__ xp) {
  __shared__ _Float16 Wl[256 * 80];
  __shared__ _Float16 xl[128 * 80];
  __shared__ float biasl[256];

  const int tid = threadIdx.x;
  const int b = blockIdx.x;
  const int w = tid >> 6;
  const int lane = tid & 63;
  const int n16 = lane & 15;
  const int q = lane >> 4;

  {
    const int jd = tid;
    const float* src = (jd < kH) ? (Wih_fw + jd * kD) : (Wih_bw + (jd - kH) * kD);
    const float4* s4 = (const float4*)src;
#pragma unroll
    for (int k = 0; k < 8; ++k) {
      float4 a = s4[2 * k], c = s4[2 * k + 1];
      half8 h;
      h[0] = (_Float16)a.x; h[1] = (_Float16)a.y; h[2] = (_Float16)a.z; h[3] = (_Float16)a.w;
      h[4] = (_Float16)c.x; h[5] = (_Float16)c.y; h[6] = (_Float16)c.z; h[7] = (_Float16)c.w;
      *(half8*)&Wl[jd * 80 + k * 8] = h;
    }
    biasl[jd] = (jd < kH) ? (bih_fw[jd] + bhh_fw[jd])
                          : (bih_bw[jd - kH] + bhh_bw[jd - kH]);
  }

  for (int ch = 0; ch < 8; ++ch) {
    __syncthreads();
    {
      const int tl = tid >> 1, hf = tid & 1;
      const float4* s4 = (const float4*)(inputs +
          ((size_t)b * kS + ch * 128 + tl) * kD + hf * 32);
#pragma unroll
      for (int k = 0; k < 4; ++k) {
        float4 a = s4[2 * k], c = s4[2 * k + 1];
        half8 h;
        h[0] = (_Float16)a.x; h[1] = (_Float16)a.y; h[2] = (_Float16)a.z; h[3] = (_Float16)a.w;
        h[4] = (_Float16)c.x; h[5] = (_Float16)c.y; h[6] = (_Float16)c.z; h[7] = (_Float16)c.w;
        *(half8*)&xl[tl * 80 + hf * 32 + k * 8] = h;
      }
    }
    __syncthreads();

    half8 bf0[4], bf1[4];
    float bs[4];
#pragma unroll
    for (int nn = 0; nn < 4; ++nn) {
      const int jd = (w * 4 + nn) * 16 + n16;
      bf0[nn] = *(const half8*)&Wl[jd * 80 + q * 8];
      bf1[nn] = *(const half8*)&Wl[jd * 80 + q * 8 + 32];
      bs[nn] = biasl[jd];
    }

#pragma unroll 2
    for (int m = 0; m < 8; ++m) {
      const int trow = m * 16 + n16;
      const half8 a0 = *(const half8*)&xl[trow * 80 + q * 8];
      const half8 a1 = *(const half8*)&xl[trow * 80 + q * 8 + 32];
#pragma unroll
      for (int nn = 0; nn < 4; ++nn) {
        f32x4 acc = {0.f, 0.f, 0.f, 0.f};
        acc = __builtin_amdgcn_mfma_f32_16x16x32_f16(a0, bf0[nn], acc, 0, 0, 0);
        acc = __builtin_amdgcn_mfma_f32_16x16x32_f16(a1, bf1[nn], acc, 0, 0, 0);
        const int jd = (w * 4 + nn) * 16 + n16;
        const int dir = jd >> 7, j = jd & 127;
        const size_t slab = (size_t)(dir * 256 + b) * (kS * kH);
#pragma unroll
        for (int r = 0; r < 4; ++r) {
          const int t = ch * 128 + m * 16 + q * 4 + r;
          const int tt = dir ? (kS - 1 - t) : t;
          xp[slab + (size_t)(tt >> 5) * (32 * kH) + (tt & 31) * kH + j] =
              (_Float16)(acc[r] + bs[nn]);
        }
      }
    }
  }
}

// =====================  Phase B: 2-wave cooperative recurrence  =================
// 512 blocks x 128 threads (2 waves = 1 chain): dir = blockIdx>>8, b = blockIdx&255.
// Wave w owns h-units [64w, 64w+64); lane L finalizes unit j = 64w+L (K=128 dot).
// Per step: own-half h (32 dwords) broadcast register-only via v_readlane from
// hp_prev; other-half h (32 dwords) via 8 uniform ds_read_b128 from jrn[prev],
// issued FIRST so LDS latency hides under the 32 readlane-dots. Exchange is one
// ds_write + lgkmcnt(0)+s_barrier per step (no vmcnt drain -> prefetch lives).
__global__ __launch_bounds__(128, 1) void birnn_step_kernel(
    const _Float16* __restrict__ xp,
    const float* __restrict__ Whh_fw, const float* __restrict__ Whh_bw,
    const float* __restrict__ fcW, const float* __restrict__ fcb,
    float* __restrict__ out) {
  const int dir = blockIdx.x >> 8;
  const int b = blockIdx.x & 255;
  const int tid = threadIdx.x;
  const int w = tid >> 6;   // wave id: which h-half this wave produces
  const int L = tid & 63;

  __shared__ unsigned jrn[32 * 68];   // h ring/journal: 32 rows x 64 dwords (+pad)
  __shared__ unsigned xbuf[2][2048];  // two 8 KB xp chunks
  __shared__ unsigned fcwl[64];       // fc weights, packed f16 pairs
  __shared__ float outw[2][kS];       // per-wave fc partials

  const float* __restrict__ Whh = dir ? Whh_bw : Whh_fw;

  // ---- weights for unit j = 64w+L, wave-relative halves (compile-time reg idx)
  unsigned wOwn[32], wOth[32];
  {
    const float* r = Whh + (size_t)(64 * w + L) * kH;
    const int own = 64 * w, oth = 64 * (1 - w);
#pragma unroll
    for (int m = 0; m < 32; ++m) {
      wOwn[m] = pk16(r[own + 2 * m], r[own + 2 * m + 1]);
      wOth[m] = pk16(r[oth + 2 * m], r[oth + 2 * m + 1]);
    }
  }
  if (w == 0) fcwl[L] = pk16(fcW[dir * kH + 2 * L], fcW[dir * kH + 2 * L + 1]);
  jrn[31 * 68 + L] = 0;  // h_{-1} = 0 (both waves cover the full row: L in [0,64))

  unsigned hp_prev = 0;  // lane-pair packed h dword from previous step

  // ---- prime xp chunks 0,1 (each wave stages its own 4 KB half) ----
  const char* slab = (const char*)(xp + (size_t)(dir * 256 + b) * (kS * kH));
  stage_half(slab, &xbuf[0][0], L, w);
  stage_half(slab + 8192, &xbuf[1][0], L, w);
  asm volatile("s_waitcnt vmcnt(4)" ::: "memory");  // own chunk-0 half resident

  for (int c = 0; c < 32; ++c) {
    const unsigned short* xs = (const unsigned short*)&xbuf[c & 1][0];

#pragma unroll 2
    for (int s = 0; s < 32; ++s) {
      wave_sync();  // jrn[prev] (other wave) + staged chunk visible
      const int prev = (s + 31) & 31;
      // other-half h: 8 uniform b128 reads, issued before the readlane dots
      const uint4* hr = (const uint4*)&jrn[prev * 68 + 32 * (1 - w)];
      uint4 hv[8];
#pragma unroll
      for (int g = 0; g < 8; ++g) hv[g] = hr[g];
      const unsigned short xraw = xs[s * 128 + 64 * w + L];

      float o0 = 0.f, o1 = 0.f, o2 = 0.f, o3 = 0.f;
      float t0 = 0.f, t1 = 0.f, t2 = 0.f, t3 = 0.f;
#pragma unroll
      for (int g = 0; g < 8; ++g) {
        const unsigned h0 = rdlane(hp_prev, 8 * g + 0);
        const unsigned h1 = rdlane(hp_prev, 8 * g + 2);
        const unsigned h2 = rdlane(hp_prev, 8 * g + 4);
        const unsigned h3 = rdlane(hp_prev, 8 * g + 6);
        o0 = fdot2(wOwn[4 * g + 0], h0, o0);
        t0 = fdot2(wOth[4 * g + 0], hv[g].x, t0);
        o1 = fdot2(wOwn[4 * g + 1], h1, o1);
        t1 = fdot2(wOth[4 * g + 1], hv[g].y, t1);
        o2 = fdot2(wOwn[4 * g + 2], h2, o2);
        t2 = fdot2(wOth[4 * g + 2], hv[g].z, t2);
        o3 = fdot2(wOwn[4 * g + 3], h3, o3);
        t3 = fdot2(wOth[4 * g + 3], hv[g].w, t3);
      }
      const float xval = (float)__builtin_bit_cast(_Float16, xraw);
      const float v = (((o0 + o1) + (o2 + o3)) + ((t0 + t1) + (t2 + t3))) + xval;
      const float h = fast_tanh(v);
      const float nb = lane_xor1(h);
      const float lo = (L & 1) ? nb : h;
      const float hi = (L & 1) ? h : nb;
      const unsigned hp = pk16(lo, hi);
      jrn[s * 68 + 32 * w + (L >> 1)] = hp;  // pair-duplicate write, same value
      hp_prev = hp;
    }

    // ---- chunk boundary: both waves done reading chunk c & jrn rows ----
    wave_sync();

    // ---- stage chunk c+2 into the freed buffer (issue before drain) ----
    if (c < 30) stage_half(slab + (size_t)(c + 2) * 8192, &xbuf[c & 1][0], L, w);

    // ---- fc drain of chunk c: own-half partials only (no cross-wave dep) ----
    {
      const int tl = L >> 1, jh = L & 1;
      const uint4* rp = (const uint4*)&jrn[tl * 68 + 32 * w + jh * 16];
      const uint4* fp = (const uint4*)&fcwl[32 * w + jh * 16];
      float acc = 0.f;
#pragma unroll
      for (int k = 0; k < 4; ++k) {
        const uint4 hv4 = rp[k];
        const uint4 fw4 = fp[k];
        acc = fdot2(fw4.x, hv4.x, acc);
        acc = fdot2(fw4.y, hv4.y, acc);
        acc = fdot2(fw4.z, hv4.z, acc);
        acc = fdot2(fw4.w, hv4.w, acc);
      }
      acc += lane_xor1(acc);
      if (jh == 0) outw[w][c * 32 + tl] = acc;
    }

    // ---- gate own half of chunk c+1 (other wave gated by its own vmcnt+barrier)
    if (c < 30) {
      asm volatile("s_waitcnt vmcnt(4)" ::: "memory");
    } else if (c == 30) {
      asm volatile("s_waitcnt vmcnt(0)" ::: "memory");
    }
  }

  __syncthreads();  // both waves' outw complete (nothing left in vmcnt queue)

  // ---- emit: sum wave partials, one atomic pass (fw adds fcb) ----
  const float fcb0 = (dir == 0) ? fcb[0] : 0.f;
#pragma unroll
  for (int k = 0; k < 8; ++k) {
    const int t = k * 128 + tid;
    const int td = dir ? (kS - 1 - t) : t;
    atomicAdd(&out[(size_t)b * kS + td], outw[0][t] + outw[1][t] + fcb0);
  }
}

}  // namespace

extern "C" void kernel_launch(void* const* d_in, const int* in_sizes, int n_in,
                              void* d_out, int out_size, void* d_ws, size_t ws_size,
                              hipStream_t stream) {
  (void)in_sizes; (void)n_in; (void)ws_size;
  const float* inputs = (const float*)d_in[0];
  const float* Wih_fw = (const float*)d_in[1];
  const float* Whh_fw = (const float*)d_in[2];
  const float* bih_fw = (const float*)d_in[3];
  const float* bhh_fw = (const float*)d_in[4];
  const float* Wih_bw = (const float*)d_in[5];
  const float* Whh_bw = (const float*)d_in[6];
  const float* bih_bw = (const float*)d_in[7];
  const float* bhh_bw = (const float*)d_in[8];
  const float* fc_W   = (const float*)d_in[9];
  const float* fc_b   = (const float*)d_in[10];
  float* out = (float*)d_out;
  _Float16* xpw = (_Float16*)d_ws;  // 2*256*1024*128 f16 = 128 MiB

  hipMemsetAsync(out, 0, (size_t)out_size * sizeof(float), stream);

  hipLaunchKernelGGL(xproj_kernel, dim3(256), dim3(256), 0, stream,
                     inputs, Wih_fw, bih_fw, bhh_fw, Wih_bw, bih_bw, bhh_bw, xpw);
  hipLaunchKernelGGL(birnn_step_kernel, dim3(512), dim3(128), 0, stream,
                     xpw, Whh_fw, Whh_bw, fc_W, fc_b, out);
}

// Round 5
// 611.190 us; speedup vs baseline: 1.1794x; 1.1794x over previous
//
#include <hip/hip_runtime.h>

namespace {

constexpr int kS = 1024;
constexpr int kD = 64;
constexpr int kH = 128;

typedef __attribute__((ext_vector_type(2))) _Float16 half2v;
typedef __attribute__((ext_vector_type(4))) float f32x4;
typedef __attribute__((ext_vector_type(8))) _Float16 half8;

__device__ __forceinline__ float fdot2(unsigned w, unsigned h, float acc) {
#if __has_builtin(__builtin_amdgcn_fdot2)
  return __builtin_amdgcn_fdot2(__builtin_bit_cast(half2v, w),
                                __builtin_bit_cast(half2v, h), acc, false);
#else
  float d;
  asm("v_dot2_f32_f16 %0, %1, %2, %3" : "=v"(d) : "v"(w), "v"(h), "v"(acc));
  return d;
#endif
}

// uniform lane-broadcast of a packed-f16 dword (register -> SGPR, no LDS)
__device__ __forceinline__ unsigned rdlane(unsigned v, int k) {
#if __has_builtin(__builtin_amdgcn_readlane)
  return (unsigned)__builtin_amdgcn_readlane((int)v, k);
#else
  return (unsigned)__shfl((int)v, k, 64);
#endif
}

// RNE f16 pack (cvt_pkrtz is RTZ -> systematic shrink bias over 1024 steps)
__device__ __forceinline__ unsigned pk16(float a, float b) {
  half2v h;
  h.x = (_Float16)a;
  h.y = (_Float16)b;
  return __builtin_bit_cast(unsigned, h);
}

__device__ __forceinline__ float fast_tanh(float x) {
#if __has_builtin(__builtin_amdgcn_fmed3f)
  x = __builtin_amdgcn_fmed3f(x, -15.f, 15.f);  // single-instr clamp
#else
  x = fminf(fmaxf(x, -15.f), 15.f);
#endif
  float e = __expf(2.f * x);
  return (e - 1.f) * __builtin_amdgcn_rcpf(e + 1.f);
}

#if __has_builtin(__builtin_amdgcn_mov_dpp)
__device__ __forceinline__ float lane_xor1(float v) {
  return __int_as_float(__builtin_amdgcn_mov_dpp(__float_as_int(v), 0xB1, 0xF, 0xF, true));
}
#else
__device__ __forceinline__ float lane_xor1(float v) {
  return __int_as_float(__builtin_amdgcn_ds_swizzle(__float_as_int(v), 0x041F));
}
#endif

// async global->LDS: 8 x 16B/lane = one 8 KB xp chunk (no VGPR round-trip)
__device__ __forceinline__ void stage_chunk(const char* g, unsigned* lds, int L) {
#pragma unroll
  for (int k = 0; k < 8; ++k) {
    __builtin_amdgcn_global_load_lds(
        (const __attribute__((address_space(1))) void*)(g + k * 1024 + L * 16),
        (__attribute__((address_space(3))) void*)(lds + k * 256), 16, 0, 0);
  }
}

// xp (f16) layout per (dir,b) slab of kS*kH elems, chunk-transposed:
//   idx = (t>>5)*(32*kH) + (t&31)*kH + j     (dir=1 pre-time-reversed)
// -> one 32-step chunk = 8 KB contiguous, DMA-stageable.

// =====================  Phase A: x-projection via f16 MFMA  =====================
// (unchanged: 84 us, correct)
__global__ __launch_bounds__(256, 2) void xproj_kernel(
    const float* __restrict__ inputs,
    const float* __restrict__ Wih_fw, const float* __restrict__ bih_fw,
    const float* __restrict__ bhh_fw,
    const float* __restrict__ Wih_bw, const float* __restrict__ bih_bw,
    const float* __restrict__ bhh_bw,
    _Float16* __restrict__ xp) {
  __shared__ _Float16 Wl[256 * 80];
  __shared__ _Float16 xl[128 * 80];
  __shared__ float biasl[256];

  const int tid = threadIdx.x;
  const int b = blockIdx.x;
  const int w = tid >> 6;
  const int lane = tid & 63;
  const int n16 = lane & 15;
  const int q = lane >> 4;

  {
    const int jd = tid;
    const float* src = (jd < kH) ? (Wih_fw + jd * kD) : (Wih_bw + (jd - kH) * kD);
    const float4* s4 = (const float4*)src;
#pragma unroll
    for (int k = 0; k < 8; ++k) {
      float4 a = s4[2 * k], c = s4[2 * k + 1];
      half8 h;
      h[0] = (_Float16)a.x; h[1] = (_Float16)a.y; h[2] = (_Float16)a.z; h[3] = (_Float16)a.w;
      h[4] = (_Float16)c.x; h[5] = (_Float16)c.y; h[6] = (_Float16)c.z; h[7] = (_Float16)c.w;
      *(half8*)&Wl[jd * 80 + k * 8] = h;
    }
    biasl[jd] = (jd < kH) ? (bih_fw[jd] + bhh_fw[jd])
                          : (bih_bw[jd - kH] + bhh_bw[jd - kH]);
  }

  for (int ch = 0; ch < 8; ++ch) {
    __syncthreads();
    {
      const int tl = tid >> 1, hf = tid & 1;
      const float4* s4 = (const float4*)(inputs +
          ((size_t)b * kS + ch * 128 + tl) * kD + hf * 32);
#pragma unroll
      for (int k = 0; k < 4; ++k) {
        float4 a = s4[2 * k], c = s4[2 * k + 1];
        half8 h;
        h[0] = (_Float16)a.x; h[1] = (_Float16)a.y; h[2] = (_Float16)a.z; h[3] = (_Float16)a.w;
        h[4] = (_Float16)c.x; h[5] = (_Float16)c.y; h[6] = (_Float16)c.z; h[7] = (_Float16)c.w;
        *(half8*)&xl[tl * 80 + hf * 32 + k * 8] = h;
      }
    }
    __syncthreads();

    half8 bf0[4], bf1[4];
    float bs[4];
#pragma unroll
    for (int nn = 0; nn < 4; ++nn) {
      const int jd = (w * 4 + nn) * 16 + n16;
      bf0[nn] = *(const half8*)&Wl[jd * 80 + q * 8];
      bf1[nn] = *(const half8*)&Wl[jd * 80 + q * 8 + 32];
      bs[nn] = biasl[jd];
    }

#pragma unroll 2
    for (int m = 0; m < 8; ++m) {
      const int trow = m * 16 + n16;
      const half8 a0 = *(const half8*)&xl[trow * 80 + q * 8];
      const half8 a1 = *(const half8*)&xl[trow * 80 + q * 8 + 32];
#pragma unroll
      for (int nn = 0; nn < 4; ++nn) {
        f32x4 acc = {0.f, 0.f, 0.f, 0.f};
        acc = __builtin_amdgcn_mfma_f32_16x16x32_f16(a0, bf0[nn], acc, 0, 0, 0);
        acc = __builtin_amdgcn_mfma_f32_16x16x32_f16(a1, bf1[nn], acc, 0, 0, 0);
        const int jd = (w * 4 + nn) * 16 + n16;
        const int dir = jd >> 7, j = jd & 127;
        const size_t slab = (size_t)(dir * 256 + b) * (kS * kH);
#pragma unroll
        for (int r = 0; r < 4; ++r) {
          const int t = ch * 128 + m * 16 + q * 4 + r;
          const int tt = dir ? (kS - 1 - t) : t;
          xp[slab + (size_t)(tt >> 5) * (32 * kH) + (tt & 31) * kH + j] =
              (_Float16)(acc[r] + bs[nn]);
        }
      }
    }
  }
}

// =====================  Phase B: wave-autonomous recurrence  =====================
// 512 blocks x 64 threads (ONE wave): dir = blockIdx>>8, b = blockIdx&255.
// Lane L finalizes j0=2L, j1=2L+1 with FULL K=128: no reduction, no barrier.
// h broadcast register-only via v_readlane, HOISTED in batches of 32 so every
// consumer sits >=60cy after its readlane (hides VALU->SGPR->VALU wait states
// without exceeding the ~102-SGPR/wave cap). Dots use 16 accumulator chains
// (depth 8, 32cy spacing) to tolerate long fdot2 accumulate latency.
__global__ __launch_bounds__(64, 1) void birnn_step_kernel(
    const _Float16* __restrict__ xp,
    const float* __restrict__ Whh_fw, const float* __restrict__ Whh_bw,
    const float* __restrict__ fcW, const float* __restrict__ fcb,
    float* __restrict__ out) {
  const int dir = blockIdx.x >> 8;
  const int b = blockIdx.x & 255;
  const int L = threadIdx.x;

  __shared__ unsigned jrn[32 * 68];   // fc journal, 68-dw rows (b128-aligned)
  __shared__ unsigned xbuf[2][2048];  // two 8 KB xp chunks
  __shared__ unsigned fcwl[64];       // fc weights, packed f16 pairs
  __shared__ float outbuf[kS];

  const float* __restrict__ Whh = dir ? Whh_bw : Whh_fw;

  // ---- weights: rows j0,j1 -> 128 packed-f16 dwords (w[k]=(W[j][2k],W[j][2k+1]))
  unsigned w0[64], w1[64];
  {
    const float* r0 = Whh + (size_t)(2 * L) * kH;
    const float* r1 = Whh + (size_t)(2 * L + 1) * kH;
#pragma unroll
    for (int k = 0; k < 64; ++k) {
      w0[k] = pk16(r0[2 * k], r0[2 * k + 1]);
      w1[k] = pk16(r1[2 * k], r1[2 * k + 1]);
    }
  }
  fcwl[L] = pk16(fcW[dir * kH + 2 * L], fcW[dir * kH + 2 * L + 1]);

  unsigned hcur = 0;  // h_{-1} = 0 (lane-local packed pair)

  // ---- prime xp chunks 0,1 ----
  const char* slab = (const char*)(xp + (size_t)(dir * 256 + b) * (kS * kH));
  stage_chunk(slab, &xbuf[0][0], L);
  stage_chunk(slab + 8192, &xbuf[1][0], L);
  asm volatile("s_waitcnt vmcnt(0)" ::: "memory");

  for (int c = 0; c < 32; ++c) {
    const unsigned* xb = &xbuf[c & 1][0];

#pragma unroll 2
    for (int s = 0; s < 32; ++s) {
      const unsigned xdw = xb[s * 64 + L];  // issue early; used after the dots
      float a[8], cc[8];
#pragma unroll
      for (int u = 0; u < 8; ++u) { a[u] = 0.f; cc[u] = 0.f; }

      unsigned hs[32];
      // ---- half 0: hoist 32 readlanes, then 64 dots (k = 0..63) ----
#pragma unroll
      for (int k = 0; k < 32; ++k) hs[k] = rdlane(hcur, k);
#pragma unroll
      for (int g = 0; g < 4; ++g) {
#pragma unroll
        for (int u = 0; u < 8; ++u) {
          a[u] = fdot2(w0[8 * g + u], hs[8 * g + u], a[u]);
          cc[u] = fdot2(w1[8 * g + u], hs[8 * g + u], cc[u]);
        }
      }
      // ---- half 1: next 32 readlanes, then 64 dots (k = 64..127) ----
#pragma unroll
      for (int k = 0; k < 32; ++k) hs[k] = rdlane(hcur, 32 + k);
#pragma unroll
      for (int g = 0; g < 4; ++g) {
#pragma unroll
        for (int u = 0; u < 8; ++u) {
          a[u] = fdot2(w0[32 + 8 * g + u], hs[8 * g + u], a[u]);
          cc[u] = fdot2(w1[32 + 8 * g + u], hs[8 * g + u], cc[u]);
        }
      }

      const half2v xh = __builtin_bit_cast(half2v, xdw);
      const float va = (((a[0] + a[1]) + (a[2] + a[3])) +
                        ((a[4] + a[5]) + (a[6] + a[7]))) + (float)xh.x;
      const float vb = (((cc[0] + cc[1]) + (cc[2] + cc[3])) +
                        ((cc[4] + cc[5]) + (cc[6] + cc[7]))) + (float)xh.y;
      hcur = pk16(fast_tanh(va), fast_tanh(vb));
      jrn[s * 68 + L] = hcur;  // journal only; not read until fc drain
    }

    // ---- fc drain of chunk c ----
    {
      const int tl = L >> 1, jh = L & 1;
      const uint4* rp = (const uint4*)&jrn[tl * 68 + jh * 32];
      const uint4* fp = (const uint4*)&fcwl[jh * 32];
      float acc = 0.f;
#pragma unroll
      for (int k = 0; k < 8; ++k) {
        const uint4 hv = rp[k];
        const uint4 fw = fp[k];
        acc = fdot2(fw.x, hv.x, acc);
        acc = fdot2(fw.y, hv.y, acc);
        acc = fdot2(fw.z, hv.z, acc);
        acc = fdot2(fw.w, hv.w, acc);
      }
      acc += lane_xor1(acc);
      if (jh == 0) outbuf[c * 32 + tl] = acc;
    }

    // ---- stage chunk c+2 into the buffer just freed; gate chunk c+1 ----
    if (c < 30) {
      stage_chunk(slab + (size_t)(c + 2) * 8192, &xbuf[c & 1][0], L);
      asm volatile("s_waitcnt vmcnt(8)" ::: "memory");
    } else if (c == 30) {
      asm volatile("s_waitcnt vmcnt(0)" ::: "memory");
    }
  }

  // ---- emit: one atomic pass (fw adds fcb) ----
  const float fcb0 = (dir == 0) ? fcb[0] : 0.f;
#pragma unroll
  for (int k = 0; k < 16; ++k) {
    const int t = L + 64 * k;
    const int td = dir ? (kS - 1 - t) : t;
    atomicAdd(&out[(size_t)b * kS + td], outbuf[t] + fcb0);
  }
}

}  // namespace

extern "C" void kernel_launch(void* const* d_in, const int* in_sizes, int n_in,
                              void* d_out, int out_size, void* d_ws, size_t ws_size,
                              hipStream_t stream) {
  (void)in_sizes; (void)n_in; (void)ws_size;
  const float* inputs = (const float*)d_in[0];
  const float* Wih_fw = (const float*)d_in[1];
  const float* Whh_fw = (const float*)d_in[2];
  const float* bih_fw = (const float*)d_in[3];
  const float* bhh_fw = (const float*)d_in[4];
  const float* Wih_bw = (const float*)d_in[5];
  const float* Whh_bw = (const float*)d_in[6];
  const float* bih_bw = (const float*)d_in[7];
  const float* bhh_bw = (const float*)d_in[8];
  const float* fc_W   = (const float*)d_in[9];
  const float* fc_b   = (const float*)d_in[10];
  float* out = (float*)d_out;
  _Float16* xpw = (_Float16*)d_ws;  // 2*256*1024*128 f16 = 128 MiB

  hipMemsetAsync(out, 0, (size_t)out_size * sizeof(float), stream);

  hipLaunchKernelGGL(xproj_kernel, dim3(256), dim3(256), 0, stream,
                     inputs, Wih_fw, bih_fw, bhh_fw, Wih_bw, bih_bw, bhh_bw, xpw);
  hipLaunchKernelGGL(birnn_step_kernel, dim3(512), dim3(64), 0, stream,
                     xpw, Whh_fw, Whh_bw, fc_W, fc_b, out);
}